// Round 3
// baseline (331.507 us; speedup 1.0000x reference)
//
#include <hip/hip_runtime.h>
#include <hip/hip_bf16.h>

// Problem constants
#define DIMD   1024
#define BATCH  4
#define SEQ    4096
#define NTOK   (BATCH * SEQ)   // 16384
#define CHUNK  64              // recurrence chunk length
#define NCHUNK (SEQ / CHUNK)   // 64

// GEMM tiling (m97 structure)
#define BM 128
#define BN 128
#define BK 32

typedef unsigned short ushort_t;
typedef __attribute__((ext_vector_type(8))) __bf16   bf16x8;
typedef __attribute__((ext_vector_type(4))) float    f32x4;
typedef __attribute__((ext_vector_type(8))) ushort_t u16x8;

__device__ __forceinline__ float b2f(ushort_t u) {
    union { unsigned int i; float f; } x;
    x.i = ((unsigned int)u) << 16;
    return x.f;
}

__device__ __forceinline__ ushort_t f2b(float f) {
    union { float f; unsigned int i; } x;
    x.f = f;
    unsigned int r = x.i + 0x7fffu + ((x.i >> 16) & 1u);  // RNE
    return (ushort_t)(r >> 16);
}

// ---------------------------------------------------------------------------
// f32 -> bf16 conversion, 8 elements/thread, 16B stores. n must be /8.
// ---------------------------------------------------------------------------
__global__ __launch_bounds__(256)
void conv_f2b(const float* __restrict__ src, ushort_t* __restrict__ dst, int n8)
{
    const int i = blockIdx.x * 256 + threadIdx.x;
    if (i >= n8) return;
    const float4* s4 = (const float4*)src;
    const float4 a = s4[i * 2];
    const float4 b = s4[i * 2 + 1];
    u16x8 o;
    o[0] = f2b(a.x); o[1] = f2b(a.y); o[2] = f2b(a.z); o[3] = f2b(a.w);
    o[4] = f2b(b.x); o[5] = f2b(b.y); o[6] = f2b(b.z); o[7] = f2b(b.w);
    *(u16x8*)(dst + (size_t)i * 8) = o;
}

// ---------------------------------------------------------------------------
// Fused kv-GEMM: computes k-tile and v-tile sharing A fragments, stores
// kv = k*v as bf16. C[n,e] = (sum_d A[n,d]Wk[e,d]) * (sum_d A[n,d]Wv[e,d]).
// ---------------------------------------------------------------------------
__global__ __launch_bounds__(256, 2)
void gemm_kv(const ushort_t* __restrict__ A,
             const ushort_t* __restrict__ Wk,
             const ushort_t* __restrict__ Wv,
             ushort_t* __restrict__ Okv)
{
    __shared__ __align__(16) ushort_t As[BM * BK];
    __shared__ __align__(16) ushort_t Bk[BN * BK];
    __shared__ __align__(16) ushort_t Bv[BN * BK];

    const int tid  = threadIdx.x;
    const int lane = tid & 63;
    const int wv   = tid >> 6;
    const int wr   = wv >> 1;
    const int wc   = wv & 1;
    const int lrow = lane & 15;
    const int kq   = lane >> 4;

    const int row0 = blockIdx.x * BM;
    const int e0   = blockIdx.y * BN;

    f32x4 ak[4][4], av[4][4];
#pragma unroll
    for (int i = 0; i < 4; i++)
#pragma unroll
        for (int j = 0; j < 4; j++) {
            ak[i][j] = f32x4{0.f, 0.f, 0.f, 0.f};
            av[i][j] = f32x4{0.f, 0.f, 0.f, 0.f};
        }

    for (int kt = 0; kt < DIMD / BK; ++kt) {
        const int k0 = kt * BK;

        __syncthreads();

        // 3 tiles x 8 KB = 1536 chunks of 16 B; 256 threads x 2 iters x 3.
#pragma unroll
        for (int it = 0; it < 2; ++it) {
            const int chunk = tid + it * 256;          // 0..511
            const int r = chunk >> 2;
            const int c = (chunk & 3) << 3;
            const ushort_t* ga = A  + (size_t)(row0 + r) * DIMD + k0 + c;
            const ushort_t* gk = Wk + (size_t)(e0 + r) * DIMD + k0 + c;
            const ushort_t* gv = Wv + (size_t)(e0 + r) * DIMD + k0 + c;
            __builtin_amdgcn_global_load_lds(
                (__attribute__((address_space(1))) void*)ga,
                (__attribute__((address_space(3))) void*)((char*)As + chunk * 16),
                16, 0, 0);
            __builtin_amdgcn_global_load_lds(
                (__attribute__((address_space(1))) void*)gk,
                (__attribute__((address_space(3))) void*)((char*)Bk + chunk * 16),
                16, 0, 0);
            __builtin_amdgcn_global_load_lds(
                (__attribute__((address_space(1))) void*)gv,
                (__attribute__((address_space(3))) void*)((char*)Bv + chunk * 16),
                16, 0, 0);
        }

        __syncthreads();

        bf16x8 af[4], bk4[4], bv4[4];
#pragma unroll
        for (int i = 0; i < 4; i++)
            af[i] = *(const bf16x8*)(As + (wr * 64 + i * 16 + lrow) * BK + kq * 8);
#pragma unroll
        for (int j = 0; j < 4; j++) {
            bk4[j] = *(const bf16x8*)(Bk + (wc * 64 + j * 16 + lrow) * BK + kq * 8);
            bv4[j] = *(const bf16x8*)(Bv + (wc * 64 + j * 16 + lrow) * BK + kq * 8);
        }

#pragma unroll
        for (int i = 0; i < 4; i++)
#pragma unroll
            for (int j = 0; j < 4; j++) {
                ak[i][j] = __builtin_amdgcn_mfma_f32_16x16x32_bf16(
                    af[i], bk4[j], ak[i][j], 0, 0, 0);
                av[i][j] = __builtin_amdgcn_mfma_f32_16x16x32_bf16(
                    af[i], bv4[j], av[i][j], 0, 0, 0);
            }
    }

    // Epilogue: kv = k*v. C/D layout: col = lane&15, row = (lane>>4)*4 + reg.
#pragma unroll
    for (int i = 0; i < 4; i++)
#pragma unroll
        for (int j = 0; j < 4; j++)
#pragma unroll
            for (int r = 0; r < 4; r++) {
                const int row = row0 + wr * 64 + i * 16 + kq * 4 + r;
                const int col = e0 + wc * 64 + j * 16 + lrow;
                Okv[(size_t)row * DIMD + col] = f2b(ak[i][j][r] * av[i][j][r]);
            }
}

// ---------------------------------------------------------------------------
// Single GEMM: C[n,e] = sum_d A[n,d] * W[e,d].
// SIG=1: sigmoid epilogue, bf16 out. F32OUT=1: plain f32 out.
// ---------------------------------------------------------------------------
template <int SIG, int F32OUT>
__global__ __launch_bounds__(256, 2)
void gemm_bt(const ushort_t* __restrict__ A,
             const ushort_t* __restrict__ W,
             ushort_t* __restrict__ Ob,
             float* __restrict__ Of)
{
    __shared__ __align__(16) ushort_t As[BM * BK];
    __shared__ __align__(16) ushort_t Bs[BN * BK];

    const int tid  = threadIdx.x;
    const int lane = tid & 63;
    const int wv   = tid >> 6;
    const int wr   = wv >> 1;
    const int wc   = wv & 1;
    const int lrow = lane & 15;
    const int kq   = lane >> 4;

    const int row0 = blockIdx.x * BM;
    const int e0   = blockIdx.y * BN;

    f32x4 acc[4][4];
#pragma unroll
    for (int i = 0; i < 4; i++)
#pragma unroll
        for (int j = 0; j < 4; j++)
            acc[i][j] = f32x4{0.f, 0.f, 0.f, 0.f};

    for (int kt = 0; kt < DIMD / BK; ++kt) {
        const int k0 = kt * BK;

        __syncthreads();

#pragma unroll
        for (int it = 0; it < 2; ++it) {
            const int chunk = tid + it * 256;
            const int r = chunk >> 2;
            const int c = (chunk & 3) << 3;
            const ushort_t* ga = A + (size_t)(row0 + r) * DIMD + k0 + c;
            const ushort_t* gb = W + (size_t)(e0 + r) * DIMD + k0 + c;
            __builtin_amdgcn_global_load_lds(
                (__attribute__((address_space(1))) void*)ga,
                (__attribute__((address_space(3))) void*)((char*)As + chunk * 16),
                16, 0, 0);
            __builtin_amdgcn_global_load_lds(
                (__attribute__((address_space(1))) void*)gb,
                (__attribute__((address_space(3))) void*)((char*)Bs + chunk * 16),
                16, 0, 0);
        }

        __syncthreads();

        bf16x8 af[4], bfr[4];
#pragma unroll
        for (int i = 0; i < 4; i++)
            af[i] = *(const bf16x8*)(As + (wr * 64 + i * 16 + lrow) * BK + kq * 8);
#pragma unroll
        for (int j = 0; j < 4; j++)
            bfr[j] = *(const bf16x8*)(Bs + (wc * 64 + j * 16 + lrow) * BK + kq * 8);

#pragma unroll
        for (int i = 0; i < 4; i++)
#pragma unroll
            for (int j = 0; j < 4; j++)
                acc[i][j] = __builtin_amdgcn_mfma_f32_16x16x32_bf16(
                    af[i], bfr[j], acc[i][j], 0, 0, 0);
    }

#pragma unroll
    for (int i = 0; i < 4; i++)
#pragma unroll
        for (int j = 0; j < 4; j++)
#pragma unroll
            for (int r = 0; r < 4; r++) {
                const int row = row0 + wr * 64 + i * 16 + kq * 4 + r;
                const int col = e0 + wc * 64 + j * 16 + lrow;
                float val = acc[i][j][r];
                if (F32OUT) {
                    Of[(size_t)row * DIMD + col] = val;
                } else {
                    if (SIG) val = 1.f / (1.f + __expf(-val));
                    Ob[(size_t)row * DIMD + col] = f2b(val);
                }
            }
}

// ---------------------------------------------------------------------------
// Pass 1: per-chunk weighted sums of kv. One thread per (b, chunk, d).
// ---------------------------------------------------------------------------
__global__ __launch_bounds__(256)
void chunk_agg(const ushort_t* __restrict__ kvb,
               const float* __restrict__ td, float* __restrict__ cs)
{
    const int idx = blockIdx.x * 256 + threadIdx.x;  // (b*NCHUNK + c)*DIMD + d
    const int d  = idx & (DIMD - 1);
    const int bc = idx >> 10;
    const int c  = bc & (NCHUNK - 1);
    const int b  = bc >> 6;

    const float decay = __expf(-__expf(td[d]));

    size_t off = ((size_t)b * SEQ + (size_t)c * CHUNK) * DIMD + d;
    float s = 0.f;
#pragma unroll 8
    for (int i = 0; i < CHUNK; i++) {
        s = decay * s + b2f(kvb[off]);
        off += DIMD;
    }
    cs[idx] = s;
}

// ---------------------------------------------------------------------------
// Pass 2: scan across chunks. One thread per (b, d). Replaces cs[c] with the
// incoming state for chunk c.
// ---------------------------------------------------------------------------
__global__ __launch_bounds__(256)
void chunk_scan(float* __restrict__ cs, const float* __restrict__ td)
{
    const int idx = blockIdx.x * 256 + threadIdx.x;  // b*DIMD + d, 4096 total
    const int d = idx & (DIMD - 1);
    const int b = idx >> 10;

    const float w      = -__expf(td[d]);
    const float decayL = __expf(w * (float)CHUNK);

    float st = 0.f;
    for (int c = 0; c < NCHUNK; c++) {
        const size_t o = ((size_t)b * NCHUNK + c) * DIMD + d;
        const float sc = cs[o];
        cs[o] = st;
        st = decayL * st + sc;
    }
}

// ---------------------------------------------------------------------------
// Pass 3: out_pre = r * (state + eu*kv); state = decay*state + kv.
// ---------------------------------------------------------------------------
__global__ __launch_bounds__(256)
void emit(const ushort_t* __restrict__ kvb, const ushort_t* __restrict__ rb,
          const float* __restrict__ td, const float* __restrict__ tf,
          const float* __restrict__ cs, ushort_t* __restrict__ op)
{
    const int idx = blockIdx.x * 256 + threadIdx.x;
    const int d  = idx & (DIMD - 1);
    const int bc = idx >> 10;
    const int c  = bc & (NCHUNK - 1);
    const int b  = bc >> 6;

    const float decay = __expf(-__expf(td[d]));
    const float eu    = __expf(tf[d]);

    float st = cs[idx];
    size_t off = ((size_t)b * SEQ + (size_t)c * CHUNK) * DIMD + d;
#pragma unroll 8
    for (int i = 0; i < CHUNK; i++) {
        const float kv = b2f(kvb[off]);
        const float rr = b2f(rb[off]);
        op[off] = f2b(rr * (st + eu * kv));
        st = decay * st + kv;
        off += DIMD;
    }
}

// ---------------------------------------------------------------------------
// Workspace budget: 41 MiB total (xb/pbuf 32 + weights 8 + cs 1).
// d_out (64 MiB) doubles as scratch for kvbuf+rbuf (dead before final GEMM).
// ---------------------------------------------------------------------------
extern "C" void kernel_launch(void* const* d_in, const int* in_sizes, int n_in,
                              void* d_out, int out_size, void* d_ws, size_t ws_size,
                              hipStream_t stream)
{
    const float* x  = (const float*)d_in[0];
    const float* Wk = (const float*)d_in[1];
    const float* Wv = (const float*)d_in[2];
    const float* Wr = (const float*)d_in[3];
    const float* Wo = (const float*)d_in[4];
    const float* td = (const float*)d_in[5];
    const float* tf = (const float*)d_in[6];

    // ws layout (41 MiB)
    ushort_t* xb   = (ushort_t*)d_ws;                        // 32 MiB; reused as pbuf
    ushort_t* Wkb  = xb  + (size_t)NTOK * DIMD;              // 2 MiB
    ushort_t* Wvb  = Wkb + (size_t)DIMD * DIMD;              // 2 MiB
    ushort_t* Wrb  = Wvb + (size_t)DIMD * DIMD;              // 2 MiB
    ushort_t* Wob  = Wrb + (size_t)DIMD * DIMD;              // 2 MiB
    float*    cs   = (float*)(Wob + (size_t)DIMD * DIMD);    // 1 MiB
    ushort_t* pbuf = xb;                                     // alias: xb dead after GEMMs

    // d_out doubles as scratch (64 MiB): kvbuf + rbuf, dead before final GEMM
    ushort_t* kvb = (ushort_t*)d_out;                        // 32 MiB
    ushort_t* rb  = kvb + (size_t)NTOK * DIMD;               // 32 MiB
    float*    out = (float*)d_out;

    // 0) convert x and weights to bf16
    conv_f2b<<<(NTOK * DIMD / 8 + 255) / 256, 256, 0, stream>>>(x, xb, NTOK * DIMD / 8);
    conv_f2b<<<(DIMD * DIMD / 8 + 255) / 256, 256, 0, stream>>>(Wk, Wkb, DIMD * DIMD / 8);
    conv_f2b<<<(DIMD * DIMD / 8 + 255) / 256, 256, 0, stream>>>(Wv, Wvb, DIMD * DIMD / 8);
    conv_f2b<<<(DIMD * DIMD / 8 + 255) / 256, 256, 0, stream>>>(Wr, Wrb, DIMD * DIMD / 8);
    conv_f2b<<<(DIMD * DIMD / 8 + 255) / 256, 256, 0, stream>>>(Wo, Wob, DIMD * DIMD / 8);

    // 1) kv = (x@Wk^T) * (x@Wv^T), fused
    gemm_kv<<<dim3(NTOK / BM, DIMD / BN), 256, 0, stream>>>(xb, Wkb, Wvb, kvb);

    // 2) r = sigmoid(x@Wr^T)
    gemm_bt<1, 0><<<dim3(NTOK / BM, DIMD / BN), 256, 0, stream>>>(xb, Wrb, rb, nullptr);

    // 3) per-chunk aggregates
    chunk_agg<<<(BATCH * NCHUNK * DIMD) / 256, 256, 0, stream>>>(kvb, td, cs);

    // 4) scan over chunk boundaries
    chunk_scan<<<(BATCH * DIMD) / 256, 256, 0, stream>>>(cs, td);

    // 5) out_pre = r*(state + eu*kv) -> pbuf (reuses xb region)
    emit<<<(BATCH * NCHUNK * DIMD) / 256, 256, 0, stream>>>(kvb, rb, td, tf, cs, pbuf);

    // 6) out = out_pre @ Wo^T (f32 epilogue, overwrites d_out)
    gemm_bt<0, 1><<<dim3(NTOK / BM, DIMD / BN), 256, 0, stream>>>(pbuf, Wob, nullptr, out);
}